// Round 7
// baseline (318.393 us; speedup 1.0000x reference)
//
#include <hip/hip_runtime.h>
#include <hip/hip_bf16.h>

// ---------------------------------------------------------------------------
// Attention_CA: out = Proj( Softmax(mask, scale * (q Wq^T) (kv Wkv^T)_K^T) (kv Wkv^T)_V )
// B=4, N=1024, M=2048, C=768, H=12, d=64.
// Round 7: attn waves split over m (4 windows) x q (2 halves), 512-thread
// blocks. K direct global->reg (no LDS), Q in regs, V double-buffered in LDS
// (1 barrier/tile). Epilogue: ds_add_f32 O/l reduction. fp16 pipe, fp32 accum.
// ---------------------------------------------------------------------------

typedef short    s16x8  __attribute__((ext_vector_type(8)));
typedef short    s16x4  __attribute__((ext_vector_type(4)));
typedef float    f32x4  __attribute__((ext_vector_type(4)));
typedef _Float16 f16x8  __attribute__((ext_vector_type(8)));
typedef _Float16 f16x4  __attribute__((ext_vector_type(4)));
typedef _Float16 f16x2  __attribute__((ext_vector_type(2)));

#define NUM_H 12
#define DIM   768
#define NQ    1024
#define MK    2048
#define QK_SCALE_LOG2E 0.18033688f

__device__ __forceinline__ short f2h(float v) {
    _Float16 h = (_Float16)v;
    return __builtin_bit_cast(short, h);
}
__device__ __forceinline__ f32x4 mfma16x32(f16x8 a, f16x8 b, f32x4 c) {
    return __builtin_amdgcn_mfma_f32_16x16x32_f16(a, b, c, 0, 0, 0);
}
__device__ __forceinline__ f32x4 mfma16x16(f16x4 a, f16x4 b, f32x4 c) {
    return __builtin_amdgcn_mfma_f32_16x16x16f16(a, b, c, 0, 0, 0);
}
__device__ __forceinline__ f16x2 pk2h(float a, float b) {
    return __builtin_bit_cast(f16x2, __builtin_amdgcn_cvt_pkrtz(a, b));
}

// ------------------- prep: all casts + mask byte-pack ----------------------
__global__ __launch_bounds__(256) void prep_kernel(
    const float* __restrict__ q, const float* __restrict__ kv,
    const float* __restrict__ Wq, const float* __restrict__ Wkv,
    const float* __restrict__ Wp, const int* __restrict__ mask,
    short* __restrict__ q_h, short* __restrict__ kv_h,
    short* __restrict__ Wq_h, short* __restrict__ Wkv_h,
    short* __restrict__ Wp_h, unsigned char* __restrict__ mbytes)
{
    int bid = blockIdx.x;
    if (bid < 5760) {
        const float* s; short* d; long base;
        if (bid < 1536)      { s = q;   d = q_h;   base = (long)bid * 2048; }
        else if (bid < 4608) { s = kv;  d = kv_h;  base = (long)(bid - 1536) * 2048; }
        else if (bid < 4896) { s = Wq;  d = Wq_h;  base = (long)(bid - 4608) * 2048; }
        else if (bid < 5472) { s = Wkv; d = Wkv_h; base = (long)(bid - 4896) * 2048; }
        else                 { s = Wp;  d = Wp_h;  base = (long)(bid - 5472) * 2048; }
        long i = base + threadIdx.x * 8;
        float4 a = *(const float4*)(s + i);
        float4 b = *(const float4*)(s + i + 4);
        s16x8 r;
        r[0] = f2h(a.x); r[1] = f2h(a.y); r[2] = f2h(a.z); r[3] = f2h(a.w);
        r[4] = f2h(b.x); r[5] = f2h(b.y); r[6] = f2h(b.z); r[7] = f2h(b.w);
        *(s16x8*)(d + i) = r;
    } else {
        long base = (long)(bid - 5760) * 2048 + threadIdx.x * 8;
        int4 m0 = *(const int4*)(mask + base);
        int4 m1 = *(const int4*)(mask + base + 4);
        unsigned v = (unsigned)(m0.x != 0)        | ((unsigned)(m0.y != 0) << 1)
                   | ((unsigned)(m0.z != 0) << 2) | ((unsigned)(m0.w != 0) << 3)
                   | ((unsigned)(m1.x != 0) << 4) | ((unsigned)(m1.y != 0) << 5)
                   | ((unsigned)(m1.z != 0) << 6) | ((unsigned)(m1.w != 0) << 7);
        mbytes[base >> 3] = (unsigned char)v;
    }
}

// ---------------------------- GEMM core: C = A @ Bt^T ----------------------
__device__ __forceinline__ void gemm_core(
    short* smem,
    const short* __restrict__ A, const short* __restrict__ Bt,
    int Ncols, int mode, const float* __restrict__ bias,
    short* __restrict__ outb, short* __restrict__ outb2,
    float* __restrict__ outf, int bid)
{
    short (*As)[72] = (short(*)[72])smem;
    short (*Bs)[72] = (short(*)[72])(smem + 9216);

    int ntiles = Ncols >> 7;
    int m0 = (bid / ntiles) << 7;
    int n0 = (bid % ntiles) << 7;
    int t = threadIdx.x;
    int w = t >> 6, lane = t & 63, quad = lane >> 4, l16 = lane & 15;
    int wm = (w & 1) << 6, wn = (w >> 1) << 6;

    f32x4 zero4 = {0.f, 0.f, 0.f, 0.f};
    f32x4 acc[4][4];
    for (int i = 0; i < 4; i++)
        for (int j = 0; j < 4; j++) acc[i][j] = zero4;

    int lr = t >> 1;
    int lc = (t & 1) << 5;
    const short* Ap = A + (long)(m0 + lr) * DIM + lc;
    const short* Bp = Bt + (long)(n0 + lr) * DIM + lc;

    s16x8 a8[4], b8[4];
    #pragma unroll
    for (int c = 0; c < 4; c++) {
        a8[c] = *(const s16x8*)(Ap + c * 8);
        b8[c] = *(const s16x8*)(Bp + c * 8);
    }

    for (int kt = 0; kt < DIM; kt += 64) {
        __syncthreads();
        #pragma unroll
        for (int c = 0; c < 4; c++) {
            *(s16x8*)&As[lr][lc + c * 8] = a8[c];
            *(s16x8*)&Bs[lr][lc + c * 8] = b8[c];
        }
        __syncthreads();
        if (kt + 64 < DIM) {
            #pragma unroll
            for (int c = 0; c < 4; c++) {
                a8[c] = *(const s16x8*)(Ap + kt + 64 + c * 8);
                b8[c] = *(const s16x8*)(Bp + kt + 64 + c * 8);
            }
        }
        #pragma unroll
        for (int kh = 0; kh < 2; kh++) {
            f16x8 af[4], bfr[4];
            #pragma unroll
            for (int i = 0; i < 4; i++) {
                s16x8 tmp = *(const s16x8*)&As[wm + i * 16 + l16][kh * 32 + quad * 8];
                af[i] = __builtin_bit_cast(f16x8, tmp);
            }
            #pragma unroll
            for (int j = 0; j < 4; j++) {
                s16x8 tmp = *(const s16x8*)&Bs[wn + j * 16 + l16][kh * 32 + quad * 8];
                bfr[j] = __builtin_bit_cast(f16x8, tmp);
            }
            #pragma unroll
            for (int i = 0; i < 4; i++)
                #pragma unroll
                for (int j = 0; j < 4; j++)
                    acc[i][j] = mfma16x32(af[i], bfr[j], acc[i][j]);
        }
    }

    __syncthreads();

    if (mode == 2) {
        #pragma unroll
        for (int i = 0; i < 4; i++)
            #pragma unroll
            for (int j = 0; j < 4; j++)
                #pragma unroll
                for (int r = 0; r < 4; r++) {
                    int row = m0 + wm + i * 16 + quad * 4 + r;
                    int col = n0 + wn + j * 16 + l16;
                    outf[(long)row * DIM + col] = acc[i][j][r] + bias[col];
                }
        return;
    }

    short (*Cs)[136] = (short(*)[136])smem;
    bool vreg = (mode == 1) && (n0 >= DIM);

    if (!vreg) {
        float sc = (mode == 0) ? QK_SCALE_LOG2E : 1.0f;
        #pragma unroll
        for (int i = 0; i < 4; i++)
            #pragma unroll
            for (int j = 0; j < 4; j++)
                #pragma unroll
                for (int r = 0; r < 4; r++)
                    Cs[wm + i * 16 + quad * 4 + r][wn + j * 16 + l16] =
                        f2h(acc[i][j][r] * sc);
    } else {
        #pragma unroll
        for (int i = 0; i < 4; i++)
            #pragma unroll
            for (int j = 0; j < 4; j++) {
                int c = wn + j * 16 + l16;
                int r0 = wm + i * 16 + quad * 4;
                s16x4 pk;
                pk[0] = f2h(acc[i][j][0]); pk[1] = f2h(acc[i][j][1]);
                pk[2] = f2h(acc[i][j][2]); pk[3] = f2h(acc[i][j][3]);
                *(s16x4*)&Cs[c][r0] = pk;
            }
    }
    __syncthreads();

    if (!vreg) {
        int hb2 = n0 >> 6;
        long rowsN = (mode == 0) ? NQ : MK;
        int b = (int)(m0 / rowsN);
        int rb = (int)(m0 % rowsN);
        short* ob0 = outb + ((long)(b * NUM_H + hb2) * rowsN + rb) * 64;
        short* ob1 = outb + ((long)(b * NUM_H + hb2 + 1) * rowsN + rb) * 64;
        #pragma unroll
        for (int k2 = 0; k2 < 8; k2++) {
            int ch = k2 * 256 + t;
            int half = ch >> 10, off = ch & 1023;
            s16x8 vd = *(const s16x8*)&Cs[off >> 3][(half << 6) + ((off & 7) << 3)];
            *(s16x8*)((half ? ob1 : ob0) + off * 8) = vd;
        }
    } else {
        int hb2 = (n0 - DIM) >> 6;
        int b = m0 >> 11, rb = m0 & 2047;
        #pragma unroll
        for (int k2 = 0; k2 < 8; k2++) {
            int ch = k2 * 256 + t;
            int c = ch >> 4, woff = (ch & 15) << 3;
            s16x8 vd = *(const s16x8*)&Cs[c][woff];
            int half = c >> 6, dd = c & 63;
            *(s16x8*)(outb2 + (((long)(b * NUM_H + hb2 + half) * 64 + dd) * MK + rb) + woff) = vd;
        }
    }
}

__global__ __launch_bounds__(256) void gemm12_kernel(
    const short* __restrict__ qh, const short* __restrict__ Wqh,
    const short* __restrict__ kvh, const short* __restrict__ Wkvh,
    short* __restrict__ qp, short* __restrict__ kk, short* __restrict__ vt)
{
    __shared__ short smem[18432];
    if (blockIdx.x < 192)
        gemm_core(smem, qh, Wqh, 768, 0, nullptr, qp, nullptr, nullptr, blockIdx.x);
    else
        gemm_core(smem, kvh, Wkvh, 1536, 1, nullptr, kk, vt, nullptr, blockIdx.x - 192);
}

__global__ __launch_bounds__(256) void gemm3_kernel(
    const short* __restrict__ xb, const short* __restrict__ Wph,
    const float* __restrict__ bias, float* __restrict__ out)
{
    __shared__ short smem[18432];
    gemm_core(smem, xb, Wph, 768, 2, bias, nullptr, nullptr, out, blockIdx.x);
}

// ------------------------- flash attention (m-split waves) -----------------
// 512 threads = 8 waves: wave (wm = w&3, wq = w>>2) owns m-window
// [mt+wm*16, +16) x q-half [wq*32, +32). K: direct global A-frag loads
// (prefetched; 2nd q-half hits L1). Q: registers. V: LDS, double-buffered,
// one barrier/tile. O/l partial over m -> ds_add_f32 reduction epilogue.
__global__ __launch_bounds__(512, 4) void attn_kernel(
    const short* __restrict__ qp, const short* __restrict__ kk,
    const short* __restrict__ vt, const unsigned char* __restrict__ mb,
    short* __restrict__ xb)
{
    __shared__ char smem[27648];
    short (*qs)[72]  = (short(*)[72])smem;            // Q stage (pre-loop only)
    short (*vb0)[72] = (short(*)[72])(smem + 9216);   // V dbuf 0
    short (*vb1)[72] = (short(*)[72])(smem + 18432);  // V dbuf 1
    float* Racc = (float*)smem;                       // [64][68] fp32 (epilogue)
    float* lacc = (float*)(smem + 17408);             // [64] fp32 (epilogue)

    int bid = blockIdx.x;
    int bh = bid % 48, nt = bid / 48;                 // XCD swizzle
    int h = bh % NUM_H, b = bh / NUM_H;
    int n0 = nt << 6;
    int t = threadIdx.x;
    int w = t >> 6, lane = t & 63, quad = lane >> 4, l16 = lane & 15;
    int wm = w & 3, wq = w >> 2;

    const short* qbase = qp + ((long)bh * NQ + n0) * 64;
    const short* kbase = kk + (long)bh * MK * 64;
    const short* vbase = vt + (long)bh * 64 * MK;

    int gr = t >> 3, gc = (t & 7) << 3;               // 512-thread staging map

    // stage Q tile + V(0); prefetch V(1), K(0), mask(0)
    *(s16x8*)&qs[gr][gc] = *(const s16x8*)(qbase + gr * 64 + gc);
    const short* vptr = vbase + (long)gr * MK + gc;
    *(s16x8*)&vb0[gr][gc] = *(const s16x8*)(vptr);
    s16x8 vnext = *(const s16x8*)(vptr + 64);
    const short* kptr = kbase + (long)(wm * 16 + l16) * 64 + quad * 8;
    s16x8 kreg0 = *(const s16x8*)(kptr);
    s16x8 kreg1 = *(const s16x8*)(kptr + 32);
    const unsigned char* mrow0 =
        mb + ((long)(b * NQ + n0 + wq * 32 + l16) << 8) + (wm << 1);
    const unsigned char* mrow1 = mrow0 + (16 << 8);
    unsigned cmk0 = *(const unsigned short*)(mrow0);
    unsigned cmk1 = *(const unsigned short*)(mrow1);
    __syncthreads();

    f16x8 bq[2][2];                                   // q-half B-frags (regs)
    #pragma unroll
    for (int q2 = 0; q2 < 2; q2++)
        #pragma unroll
        for (int kh = 0; kh < 2; kh++)
            bq[q2][kh] = __builtin_bit_cast(f16x8,
                *(const s16x8*)&qs[wq * 32 + q2 * 16 + l16][kh * 32 + quad * 8]);

    f32x4 zero4 = {0.f, 0.f, 0.f, 0.f};
    f32x4 o[2][4];
    float lsum0 = 0.f, lsum1 = 0.f;
    #pragma unroll
    for (int q2 = 0; q2 < 2; q2++)
        for (int jd = 0; jd < 4; jd++) o[q2][jd] = zero4;

    for (int tt = 0; tt < 32; tt++) {
        int mt = tt << 6;
        short (*cur)[72] = (tt & 1) ? vb1 : vb0;
        short (*nxt)[72] = (tt & 1) ? vb0 : vb1;

        // S^T = K Q^T for this wave's 16-m x 32-q
        f16x8 ak0 = __builtin_bit_cast(f16x8, kreg0);
        f16x8 ak1 = __builtin_bit_cast(f16x8, kreg1);
        f32x4 s0 = zero4, s1 = zero4;
        s0 = mfma16x32(ak0, bq[0][0], s0);
        s0 = mfma16x32(ak1, bq[0][1], s0);
        s1 = mfma16x32(ak0, bq[1][0], s1);
        s1 = mfma16x32(ak1, bq[1][1], s1);

        unsigned bits0 = cmk0 >> (quad << 2);
        unsigned bits1 = cmk1 >> (quad << 2);

        if (tt < 31) {                                // prefetch K/mask, stage V
            kreg0 = *(const s16x8*)(kptr + (long)(mt + 64) * 64);
            kreg1 = *(const s16x8*)(kptr + (long)(mt + 64) * 64 + 32);
            cmk0 = *(const unsigned short*)(mrow0 + ((mt + 64) >> 3));
            cmk1 = *(const unsigned short*)(mrow1 + ((mt + 64) >> 3));
            *(s16x8*)&nxt[gr][gc] = vnext;            // V(tt+1) -> other buffer
            if (tt < 30) vnext = *(const s16x8*)(vptr + mt + 128);
        }

        // p = mask ? exp2(s) : 0 ; accumulate l ; pack fp16 K=16 A-frags
        float e0 = (bits0 & 1u)        ? __builtin_amdgcn_exp2f(s0[0]) : 0.f;
        float e1 = ((bits0 >> 1) & 1u) ? __builtin_amdgcn_exp2f(s0[1]) : 0.f;
        float e2 = ((bits0 >> 2) & 1u) ? __builtin_amdgcn_exp2f(s0[2]) : 0.f;
        float e3 = ((bits0 >> 3) & 1u) ? __builtin_amdgcn_exp2f(s0[3]) : 0.f;
        lsum0 += (e0 + e1) + (e2 + e3);
        f16x2 lo0 = pk2h(e0, e1), hi0 = pk2h(e2, e3);
        f16x4 pa0 = __builtin_shufflevector(lo0, hi0, 0, 1, 2, 3);
        float f0 = (bits1 & 1u)        ? __builtin_amdgcn_exp2f(s1[0]) : 0.f;
        float f1 = ((bits1 >> 1) & 1u) ? __builtin_amdgcn_exp2f(s1[1]) : 0.f;
        float f2 = ((bits1 >> 2) & 1u) ? __builtin_amdgcn_exp2f(s1[2]) : 0.f;
        float f3 = ((bits1 >> 3) & 1u) ? __builtin_amdgcn_exp2f(s1[3]) : 0.f;
        lsum1 += (f0 + f1) + (f2 + f3);
        f16x2 lo1 = pk2h(f0, f1), hi1 = pk2h(f2, f3);
        f16x4 pa1 = __builtin_shufflevector(lo1, hi1, 0, 1, 2, 3);

        // O += P V over this wave's m-window (V frag shared by both q-halves)
        #pragma unroll
        for (int jd = 0; jd < 4; jd++) {
            f16x4 bv = *(const f16x4*)&cur[jd * 16 + l16][(wm << 4) + (quad << 2)];
            o[0][jd] = mfma16x16(pa0, bv, o[0][jd]);
            o[1][jd] = mfma16x16(pa1, bv, o[1][jd]);
        }
        __syncthreads();   // nxt fully staged; cur reads done before overwrite
    }

    // ---- epilogue: reduce partial O / l across the 4 m-waves ----
    lsum0 += __shfl_xor(lsum0, 16); lsum0 += __shfl_xor(lsum0, 32);
    lsum1 += __shfl_xor(lsum1, 16); lsum1 += __shfl_xor(lsum1, 32);

    for (int i = t; i < 1104; i += 512)               // zero Racc(64x68)+lacc(64)
        *(f32x4*)(Racc + i * 4) = zero4;
    __syncthreads();

    #pragma unroll
    for (int q2 = 0; q2 < 2; q2++)
        #pragma unroll
        for (int jd = 0; jd < 4; jd++)
            #pragma unroll
            for (int rr = 0; rr < 4; rr++) {
                int qrow = wq * 32 + q2 * 16 + quad * 4 + rr;
                atomicAdd(&Racc[qrow * 68 + jd * 16 + l16], o[q2][jd][rr]);
            }
    if (quad == 0) {
        atomicAdd(&lacc[wq * 32 + l16], lsum0);
        atomicAdd(&lacc[wq * 32 + 16 + l16], lsum1);
    }
    __syncthreads();

    // normalize + store: thread t -> q-row t>>3, dd chunk (t&7)*8
    {
        int row = t >> 3, c8 = (t & 7) << 3;
        f32x4 va = *(const f32x4*)&Racc[row * 68 + c8];
        f32x4 vb = *(const f32x4*)&Racc[row * 68 + c8 + 4];
        float linv = 1.0f / lacc[row];
        s16x8 outv;
        outv[0] = f2h(va[0] * linv); outv[1] = f2h(va[1] * linv);
        outv[2] = f2h(va[2] * linv); outv[3] = f2h(va[3] * linv);
        outv[4] = f2h(vb[0] * linv); outv[5] = f2h(vb[1] * linv);
        outv[6] = f2h(vb[2] * linv); outv[7] = f2h(vb[3] * linv);
        *(s16x8*)(xb + ((long)b * NQ + n0 + row) * DIM + h * 64 + c8) = outv;
    }
}

// ---------------------------------------------------------------------------
extern "C" void kernel_launch(void* const* d_in, const int* in_sizes, int n_in,
                              void* d_out, int out_size, void* d_ws, size_t ws_size,
                              hipStream_t stream)
{
    const float* q     = (const float*)d_in[0];
    const float* kv    = (const float*)d_in[1];
    const float* Wq    = (const float*)d_in[2];
    const float* Wkv   = (const float*)d_in[3];
    const float* Wproj = (const float*)d_in[4];
    const float* bproj = (const float*)d_in[5];
    const int*   mask  = (const int*)d_in[6];
    float* out = (float*)d_out;

    char* ws = (char*)d_ws;
    short* q_h   = (short*)ws; ws += (size_t)4096 * 768 * 2;
    short* kv_h  = (short*)ws; ws += (size_t)8192 * 768 * 2;
    short* Wq_h  = (short*)ws; ws += (size_t)768 * 768 * 2;
    short* Wkv_h = (short*)ws; ws += (size_t)1536 * 768 * 2;
    short* Wp_h  = (short*)ws; ws += (size_t)768 * 768 * 2;
    short* qp    = (short*)ws; ws += (size_t)4096 * 768 * 2;   // [B,H,N,64] fp16
    short* kk    = (short*)ws; ws += (size_t)8192 * 768 * 2;   // [B,H,M,64] fp16
    short* vt    = (short*)ws; ws += (size_t)8192 * 768 * 2;   // [B,H,64,M] fp16
    short* xb    = (short*)ws; ws += (size_t)4096 * 768 * 2;   // [B,N,768]  fp16
    unsigned char* mbytes = (unsigned char*)ws;                // [B,N,M/8] = 1 MB

    prep_kernel<<<9856, 256, 0, stream>>>(q, kv, Wq, Wkv, Wproj, mask,
                                          q_h, kv_h, Wq_h, Wkv_h, Wp_h, mbytes);
    gemm12_kernel<<<960, 256, 0, stream>>>(q_h, Wq_h, kv_h, Wkv_h, qp, kk, vt);
    attn_kernel<<<768, 512, 0, stream>>>(qp, kk, vt, mbytes, xb);
    gemm3_kernel<<<192, 256, 0, stream>>>(xb, Wp_h, bproj, out);
}

// Round 8
// 221.426 us; speedup vs baseline: 1.4379x; 1.4379x over previous
//
#include <hip/hip_runtime.h>
#include <hip/hip_bf16.h>

// ---------------------------------------------------------------------------
// Attention_CA: out = Proj( Softmax(mask, scale * (q Wq^T) (kv Wkv^T)_K^T) (kv Wkv^T)_V )
// B=4, N=1024, M=2048, C=768, H=12, d=64.
// Round 8: attn reverted to R6 (54us; R7 m-split was latency-bound, 163us).
// gemm_core staging switched to global_load_lds dwordx4 (m97 pattern),
// unpadded [128][64] LDS tiles. fp16 pipeline, fp32 accum.
// ---------------------------------------------------------------------------

typedef short    s16x8  __attribute__((ext_vector_type(8)));
typedef short    s16x4  __attribute__((ext_vector_type(4)));
typedef float    f32x4  __attribute__((ext_vector_type(4)));
typedef _Float16 f16x8  __attribute__((ext_vector_type(8)));
typedef _Float16 f16x4  __attribute__((ext_vector_type(4)));
typedef _Float16 f16x2  __attribute__((ext_vector_type(2)));

#define NUM_H 12
#define DIM   768
#define NQ    1024
#define MK    2048
#define QK_SCALE_LOG2E 0.18033688f

__device__ __forceinline__ short f2h(float v) {
    _Float16 h = (_Float16)v;
    return __builtin_bit_cast(short, h);
}
__device__ __forceinline__ f32x4 mfma16x32(f16x8 a, f16x8 b, f32x4 c) {
    return __builtin_amdgcn_mfma_f32_16x16x32_f16(a, b, c, 0, 0, 0);
}
__device__ __forceinline__ f16x2 pk2h(float a, float b) {
    return __builtin_bit_cast(f16x2, __builtin_amdgcn_cvt_pkrtz(a, b));
}
// async global->LDS, 16B per lane; LDS dest = wave-uniform base + lane*16
__device__ __forceinline__ void gl_lds16(const short* g, short* l) {
    __builtin_amdgcn_global_load_lds(
        (const __attribute__((address_space(1))) unsigned int*)g,
        (__attribute__((address_space(3))) unsigned int*)l, 16, 0, 0);
}

// ------------------- prep: all casts + mask byte-pack ----------------------
__global__ __launch_bounds__(256) void prep_kernel(
    const float* __restrict__ q, const float* __restrict__ kv,
    const float* __restrict__ Wq, const float* __restrict__ Wkv,
    const float* __restrict__ Wp, const int* __restrict__ mask,
    short* __restrict__ q_h, short* __restrict__ kv_h,
    short* __restrict__ Wq_h, short* __restrict__ Wkv_h,
    short* __restrict__ Wp_h, unsigned char* __restrict__ mbytes)
{
    int bid = blockIdx.x;
    if (bid < 5760) {
        const float* s; short* d; long base;
        if (bid < 1536)      { s = q;   d = q_h;   base = (long)bid * 2048; }
        else if (bid < 4608) { s = kv;  d = kv_h;  base = (long)(bid - 1536) * 2048; }
        else if (bid < 4896) { s = Wq;  d = Wq_h;  base = (long)(bid - 4608) * 2048; }
        else if (bid < 5472) { s = Wkv; d = Wkv_h; base = (long)(bid - 4896) * 2048; }
        else                 { s = Wp;  d = Wp_h;  base = (long)(bid - 5472) * 2048; }
        long i = base + threadIdx.x * 8;
        float4 a = *(const float4*)(s + i);
        float4 b = *(const float4*)(s + i + 4);
        s16x8 r;
        r[0] = f2h(a.x); r[1] = f2h(a.y); r[2] = f2h(a.z); r[3] = f2h(a.w);
        r[4] = f2h(b.x); r[5] = f2h(b.y); r[6] = f2h(b.z); r[7] = f2h(b.w);
        *(s16x8*)(d + i) = r;
    } else {
        long base = (long)(bid - 5760) * 2048 + threadIdx.x * 8;
        int4 m0 = *(const int4*)(mask + base);
        int4 m1 = *(const int4*)(mask + base + 4);
        unsigned v = (unsigned)(m0.x != 0)        | ((unsigned)(m0.y != 0) << 1)
                   | ((unsigned)(m0.z != 0) << 2) | ((unsigned)(m0.w != 0) << 3)
                   | ((unsigned)(m1.x != 0) << 4) | ((unsigned)(m1.y != 0) << 5)
                   | ((unsigned)(m1.z != 0) << 6) | ((unsigned)(m1.w != 0) << 7);
        mbytes[base >> 3] = (unsigned char)v;
    }
}

// ---------------------------- GEMM core: C = A @ Bt^T ----------------------
// Staging via global_load_lds (width 16), unpadded [128][64] tiles.
// mode 0: qp scatter [B,H,N,d] fp16, *QK_SCALE_LOG2E
// mode 1: kv split -> K [B,H,M,d] fp16, V^T [B,H,d,M] fp16
// mode 2: out fp32 = v + bias[col]
__device__ __forceinline__ void gemm_core(
    short* smem,
    const short* __restrict__ A, const short* __restrict__ Bt,
    int Ncols, int mode, const float* __restrict__ bias,
    short* __restrict__ outb, short* __restrict__ outb2,
    float* __restrict__ outf, int bid)
{
    short (*As)[64] = (short(*)[64])smem;          // 16 KB
    short (*Bs)[64] = (short(*)[64])(smem + 8192); // 16 KB

    int ntiles = Ncols >> 7;
    int m0 = (bid / ntiles) << 7;
    int n0 = (bid % ntiles) << 7;
    int t = threadIdx.x;
    int w = t >> 6, lane = t & 63, quad = lane >> 4, l16 = lane & 15;
    int wm = (w & 1) << 6, wn = (w >> 1) << 6;

    f32x4 zero4 = {0.f, 0.f, 0.f, 0.f};
    f32x4 acc[4][4];
    for (int i = 0; i < 4; i++)
        for (int j = 0; j < 4; j++) acc[i][j] = zero4;

    // per-lane global src for the wave's 32 staged rows (8 rows / instr)
    const short* Ag = A + (long)(m0 + (w << 5) + (lane >> 3)) * DIM + ((lane & 7) << 3);
    const short* Bg = Bt + (long)(n0 + (w << 5) + (lane >> 3)) * DIM + ((lane & 7) << 3);
    short* Al = &As[w << 5][0];
    short* Bl = &Bs[w << 5][0];

    for (int kt = 0; kt < DIM; kt += 64) {
        __syncthreads();                    // prev MFMA LDS reads done
        #pragma unroll
        for (int i = 0; i < 4; i++) {
            gl_lds16(Ag + (long)i * 8 * DIM + kt, Al + i * 512);
            gl_lds16(Bg + (long)i * 8 * DIM + kt, Bl + i * 512);
        }
        __syncthreads();                    // drains vmcnt (loads complete)
        #pragma unroll
        for (int kh = 0; kh < 2; kh++) {
            f16x8 af[4], bfr[4];
            #pragma unroll
            for (int i = 0; i < 4; i++)
                af[i] = __builtin_bit_cast(f16x8,
                    *(const s16x8*)&As[wm + i * 16 + l16][kh * 32 + quad * 8]);
            #pragma unroll
            for (int j = 0; j < 4; j++)
                bfr[j] = __builtin_bit_cast(f16x8,
                    *(const s16x8*)&Bs[wn + j * 16 + l16][kh * 32 + quad * 8]);
            #pragma unroll
            for (int i = 0; i < 4; i++)
                #pragma unroll
                for (int j = 0; j < 4; j++)
                    acc[i][j] = mfma16x32(af[i], bfr[j], acc[i][j]);
        }
    }

    __syncthreads();   // MFMA LDS reads done; smem reusable

    if (mode == 2) {
        #pragma unroll
        for (int i = 0; i < 4; i++)
            #pragma unroll
            for (int j = 0; j < 4; j++)
                #pragma unroll
                for (int r = 0; r < 4; r++) {
                    int row = m0 + wm + i * 16 + quad * 4 + r;
                    int col = n0 + wn + j * 16 + l16;
                    outf[(long)row * DIM + col] = acc[i][j][r] + bias[col];
                }
        return;
    }

    short (*Cs)[136] = (short(*)[136])smem;          // 34.8 KB of the 36.9
    bool vreg = (mode == 1) && (n0 >= DIM);

    if (!vreg) {
        float sc = (mode == 0) ? QK_SCALE_LOG2E : 1.0f;
        #pragma unroll
        for (int i = 0; i < 4; i++)
            #pragma unroll
            for (int j = 0; j < 4; j++)
                #pragma unroll
                for (int r = 0; r < 4; r++)
                    Cs[wm + i * 16 + quad * 4 + r][wn + j * 16 + l16] =
                        f2h(acc[i][j][r] * sc);
    } else {
        #pragma unroll
        for (int i = 0; i < 4; i++)
            #pragma unroll
            for (int j = 0; j < 4; j++) {
                int c = wn + j * 16 + l16;
                int r0 = wm + i * 16 + quad * 4;
                s16x4 pk;
                pk[0] = f2h(acc[i][j][0]); pk[1] = f2h(acc[i][j][1]);
                pk[2] = f2h(acc[i][j][2]); pk[3] = f2h(acc[i][j][3]);
                *(s16x4*)&Cs[c][r0] = pk;            // transposed: Cs[dd][m]
            }
    }
    __syncthreads();

    if (!vreg) {
        int hb2 = n0 >> 6;
        long rowsN = (mode == 0) ? NQ : MK;
        int b = (int)(m0 / rowsN);
        int rb = (int)(m0 % rowsN);
        short* ob0 = outb + ((long)(b * NUM_H + hb2) * rowsN + rb) * 64;
        short* ob1 = outb + ((long)(b * NUM_H + hb2 + 1) * rowsN + rb) * 64;
        #pragma unroll
        for (int k2 = 0; k2 < 8; k2++) {
            int ch = k2 * 256 + t;
            int half = ch >> 10, off = ch & 1023;
            s16x8 vd = *(const s16x8*)&Cs[off >> 3][(half << 6) + ((off & 7) << 3)];
            *(s16x8*)((half ? ob1 : ob0) + off * 8) = vd;
        }
    } else {
        int hb2 = (n0 - DIM) >> 6;
        int b = m0 >> 11, rb = m0 & 2047;
        #pragma unroll
        for (int k2 = 0; k2 < 8; k2++) {
            int ch = k2 * 256 + t;
            int c = ch >> 4, woff = (ch & 15) << 3;
            s16x8 vd = *(const s16x8*)&Cs[c][woff];
            int half = c >> 6, dd = c & 63;
            *(s16x8*)(outb2 + (((long)(b * NUM_H + hb2 + half) * 64 + dd) * MK + rb) + woff) = vd;
        }
    }
}

__global__ __launch_bounds__(256) void gemm12_kernel(
    const short* __restrict__ qh, const short* __restrict__ Wqh,
    const short* __restrict__ kvh, const short* __restrict__ Wkvh,
    short* __restrict__ qp, short* __restrict__ kk, short* __restrict__ vt)
{
    __shared__ short smem[18432];
    if (blockIdx.x < 192)
        gemm_core(smem, qh, Wqh, 768, 0, nullptr, qp, nullptr, nullptr, blockIdx.x);
    else
        gemm_core(smem, kvh, Wkvh, 1536, 1, nullptr, kk, vt, nullptr, blockIdx.x - 192);
}

__global__ __launch_bounds__(256) void gemm3_kernel(
    const short* __restrict__ xb, const short* __restrict__ Wph,
    const float* __restrict__ bias, float* __restrict__ out)
{
    __shared__ short smem[18432];
    gemm_core(smem, xb, Wph, 768, 2, bias, nullptr, nullptr, out, blockIdx.x);
}

// ------------------------- flash attention (R6, 54us) ----------------------
// 4 waves x 16 q-rows. K-tile rows PERMUTED at staging so S^T lands in fp16
// K=32 A-fragment order -> PV: 10x mfma_16x16x32, V frags via ds_read_b128.
__global__ __launch_bounds__(256) void attn_kernel(
    const short* __restrict__ qp, const short* __restrict__ kk,
    const short* __restrict__ vt, const unsigned* __restrict__ mb,
    short* __restrict__ xb)
{
    __shared__ short qs[64][72];       // Q tile; reused as O staging
    __shared__ short ks[64][72];       // K tile, rows permuted
    __shared__ short vs[64][72];       // V^T tile [dd][m]

    int bid = blockIdx.x;
    int bh = bid % 48;                 // XCD swizzle: head bh -> XCD bh%8
    int nt = bid / 48;
    int h = bh % NUM_H, b = bh / NUM_H;
    int n0 = nt << 6;
    int t = threadIdx.x, w = t >> 6, lane = t & 63, quad = lane >> 4, l16 = lane & 15;

    const short* qbase = qp + ((long)bh * NQ + n0) * 64;
    const short* kbase = kk + (long)bh * MK * 64;
    const short* vbase = vt + (long)bh * 64 * MK;
    const unsigned* mrow = mb + ((long)b * NQ + n0 + (w << 4) + l16) * 64;

    {   // stage Q tile once
        int qr = t >> 2, c0 = (t & 3) << 4;
        *(s16x8*)&qs[qr][c0]     = *(const s16x8*)(qbase + qr * 64 + c0);
        *(s16x8*)&qs[qr][c0 + 8] = *(const s16x8*)(qbase + qr * 64 + c0 + 8);
    }
    __syncthreads();
    f16x8 bq[2];                       // B-frag: this wave's 16 q-rows
    #pragma unroll
    for (int kh = 0; kh < 2; kh++)
        bq[kh] = __builtin_bit_cast(f16x8,
            *(const s16x8*)&qs[(w << 4) + l16][kh * 32 + quad * 8]);

    int sr = t >> 2, c0 = (t & 3) << 4;
    // permuted K staging row
    int pr = (sr & 32) + ((sr & 4) << 2) + ((sr & 24) >> 1) + (sr & 3);
    const short* kp = kbase + (long)sr * 64 + c0;
    const short* vp = vbase + (long)sr * MK + c0;

    s16x8 k0 = *(const s16x8*)(kp);
    s16x8 k1 = *(const s16x8*)(kp + 8);
    s16x8 v0 = *(const s16x8*)(vp);
    s16x8 v1 = *(const s16x8*)(vp + 8);
    uint2 mwv = *(const uint2*)(mrow);

    f32x4 zero4 = {0.f, 0.f, 0.f, 0.f};
    f32x4 o[4], ol = zero4;
    for (int j = 0; j < 4; j++) o[j] = zero4;
    const f16x8 ones = {(_Float16)1.f, (_Float16)1.f, (_Float16)1.f, (_Float16)1.f,
                        (_Float16)1.f, (_Float16)1.f, (_Float16)1.f, (_Float16)1.f};

    for (int mt = 0; mt < MK; mt += 64) {
        __syncthreads();
        *(s16x8*)&ks[pr][c0]     = k0;
        *(s16x8*)&ks[pr][c0 + 8] = k1;
        *(s16x8*)&vs[sr][c0]     = v0;
        *(s16x8*)&vs[sr][c0 + 8] = v1;
        unsigned cm0 = mwv.x, cm1 = mwv.y;      // save pre-clobber
        __syncthreads();
        if (mt + 64 < MK) {
            k0 = *(const s16x8*)(kp + (long)(mt + 64) * 64);
            k1 = *(const s16x8*)(kp + (long)(mt + 64) * 64 + 8);
            v0 = *(const s16x8*)(vp + mt + 64);
            v1 = *(const s16x8*)(vp + mt + 64 + 8);
            mwv = *(const uint2*)(mrow + ((mt + 64) >> 5));
        }

        // S^T = K Q^T; s[jj=j2*2+sub][rr] = S[qrow=l16][m=j2*32+quad*8+sub*4+rr]
        f32x4 s[4];
        #pragma unroll
        for (int jj = 0; jj < 4; jj++) s[jj] = zero4;
        #pragma unroll
        for (int kh = 0; kh < 2; kh++)
            #pragma unroll
            for (int jj = 0; jj < 4; jj++) {
                f16x8 ak = __builtin_bit_cast(f16x8,
                    *(const s16x8*)&ks[jj * 16 + l16][kh * 32 + quad * 8]);
                s[jj] = mfma16x32(ak, bq[kh], s[jj]);
            }

        // p = mask ? exp2(s) : 0, packed to K=32 fp16 A-fragments
        f16x8 pa[2];
        #pragma unroll
        for (int j2 = 0; j2 < 2; j2++) {
            unsigned wsel = j2 ? cm1 : cm0;
            f16x2 pk[4];
            #pragma unroll
            for (int sub = 0; sub < 2; sub++) {
                unsigned bits = wsel >> ((quad << 3) + (sub << 2));
                const f32x4& sv = s[j2 * 2 + sub];
                float p0 = (bits & 1u)        ? __builtin_amdgcn_exp2f(sv[0]) : 0.f;
                float p1 = ((bits >> 1) & 1u) ? __builtin_amdgcn_exp2f(sv[1]) : 0.f;
                float p2 = ((bits >> 2) & 1u) ? __builtin_amdgcn_exp2f(sv[2]) : 0.f;
                float p3 = ((bits >> 3) & 1u) ? __builtin_amdgcn_exp2f(sv[3]) : 0.f;
                pk[sub * 2]     = pk2h(p0, p1);
                pk[sub * 2 + 1] = pk2h(p2, p3);
            }
            f16x4 lo = __builtin_shufflevector(pk[0], pk[1], 0, 1, 2, 3);
            f16x4 hi = __builtin_shufflevector(pk[2], pk[3], 0, 1, 2, 3);
            pa[j2] = __builtin_shufflevector(lo, hi, 0, 1, 2, 3, 4, 5, 6, 7);
        }

        // O += P V ; l += P ones   (K=32: 10 MFMAs, V frags via b128)
        #pragma unroll
        for (int j2 = 0; j2 < 2; j2++) {
            ol = mfma16x32(pa[j2], ones, ol);
            #pragma unroll
            for (int jd = 0; jd < 4; jd++) {
                f16x8 bv = __builtin_bit_cast(f16x8,
                    *(const s16x8*)&vs[jd * 16 + l16][j2 * 32 + quad * 8]);
                o[jd] = mfma16x32(pa[j2], bv, o[jd]);
            }
        }
    }

    // epilogue: normalize, stage via this wave's 16 qs rows, coalesced store
    float linv[4];
    #pragma unroll
    for (int rr = 0; rr < 4; rr++) linv[rr] = 1.0f / ol[rr];
    short (*ps)[72] = (short(*)[72])&qs[w << 4];   // wave-private 16 rows
    #pragma unroll
    for (int jd = 0; jd < 4; jd++)
        #pragma unroll
        for (int rr = 0; rr < 4; rr++)
            ps[quad * 4 + rr][jd * 16 + l16] = f2h(o[jd][rr] * linv[rr]);

    #pragma unroll
    for (int k2 = 0; k2 < 2; k2++) {
        int row = (lane >> 3) + k2 * 8;
        int cc = (lane & 7) << 3;
        s16x8 vd = *(const s16x8*)&ps[row][cc];
        *(s16x8*)(xb + ((long)b * NQ + n0 + (w << 4) + row) * DIM + h * 64 + cc) = vd;
    }
}

// ---------------------------------------------------------------------------
extern "C" void kernel_launch(void* const* d_in, const int* in_sizes, int n_in,
                              void* d_out, int out_size, void* d_ws, size_t ws_size,
                              hipStream_t stream)
{
    const float* q     = (const float*)d_in[0];
    const float* kv    = (const float*)d_in[1];
    const float* Wq    = (const float*)d_in[2];
    const float* Wkv   = (const float*)d_in[3];
    const float* Wproj = (const float*)d_in[4];
    const float* bproj = (const float*)d_in[5];
    const int*   mask  = (const int*)d_in[6];
    float* out = (float*)d_out;

    char* ws = (char*)d_ws;
    short* q_h   = (short*)ws; ws += (size_t)4096 * 768 * 2;
    short* kv_h  = (short*)ws; ws += (size_t)8192 * 768 * 2;
    short* Wq_h  = (short*)ws; ws += (size_t)768 * 768 * 2;
    short* Wkv_h = (short*)ws; ws += (size_t)1536 * 768 * 2;
    short* Wp_h  = (short*)ws; ws += (size_t)768 * 768 * 2;
    short* qp    = (short*)ws; ws += (size_t)4096 * 768 * 2;   // [B,H,N,64] fp16
    short* kk    = (short*)ws; ws += (size_t)8192 * 768 * 2;   // [B,H,M,64] fp16
    short* vt    = (short*)ws; ws += (size_t)8192 * 768 * 2;   // [B,H,64,M] fp16
    short* xb    = (short*)ws; ws += (size_t)4096 * 768 * 2;   // [B,N,768]  fp16
    unsigned char* mbytes = (unsigned char*)ws;                // [B,N,M/8] = 1 MB

    prep_kernel<<<9856, 256, 0, stream>>>(q, kv, Wq, Wkv, Wproj, mask,
                                          q_h, kv_h, Wq_h, Wkv_h, Wp_h, mbytes);
    gemm12_kernel<<<960, 256, 0, stream>>>(q_h, Wq_h, kv_h, Wkv_h, qp, kk, vt);
    attn_kernel<<<768, 256, 0, stream>>>(qp, kk, vt, (const unsigned*)mbytes, xb);
    gemm3_kernel<<<192, 256, 0, stream>>>(xb, Wp_h, bproj, out);
}